// Round 9
// baseline (413.513 us; speedup 1.0000x reference)
//
#include <hip/hip_runtime.h>
#include <hip/hip_bf16.h>

#define B_ 4
#define S_ 1024
#define E_ 1024
#define H_ 16
#define D_ 64

typedef __attribute__((ext_vector_type(8))) short short8;
typedef __attribute__((ext_vector_type(4))) float f32x4;

static __device__ __forceinline__ unsigned short f2bf(float x) {
  unsigned int u = __float_as_uint(x);
  unsigned int r = u + 0x7fffu + ((u >> 16) & 1u);  // round-to-nearest-even
  return (unsigned short)(r >> 16);
}
static __device__ __forceinline__ float bf2f(unsigned short b) {
  return __uint_as_float((unsigned int)b << 16);
}

#define GL2LDS16(g, l)                                                            \
  __builtin_amdgcn_global_load_lds(                                               \
      (const __attribute__((address_space(1))) unsigned int*)(g),                 \
      (__attribute__((address_space(3))) unsigned int*)(l), 16, 0, 0)

// ---------- fused preprocessing: mask|mask^T, x->bf16, W->Wt bf16 ----------
__global__ __launch_bounds__(256) void prep_kernel(const int* __restrict__ mask,
                                                   const float* __restrict__ x,
                                                   const float* __restrict__ Wq,
                                                   const float* __restrict__ Wk,
                                                   unsigned char* __restrict__ msym,
                                                   unsigned short* __restrict__ xbf,
                                                   unsigned short* __restrict__ Wt) {
  __shared__ __align__(16) char u_lds[32 * 33 * 4];
  const int blk = blockIdx.x;
  const int tid = threadIdx.x;
  if (blk < 4096) {
    int (*T)[33] = (int(*)[33])u_lds;
    const int b = blk >> 10;
    const int rest = blk & 1023;
    const int i0 = (rest >> 5) << 5;
    const int j0 = (rest & 31) << 5;
    const int ii = tid >> 3;
    const int jj4 = (tid & 7) << 2;
    const size_t bO = (size_t)b * S_ * S_;
    const int4 m2 = *(const int4*)&mask[bO + (size_t)(j0 + ii) * S_ + i0 + jj4];
    T[ii][jj4 + 0] = m2.x; T[ii][jj4 + 1] = m2.y; T[ii][jj4 + 2] = m2.z; T[ii][jj4 + 3] = m2.w;
    __syncthreads();
    const int4 m1 = *(const int4*)&mask[bO + (size_t)(i0 + ii) * S_ + j0 + jj4];
    uchar4 o;
    o.x = ((m1.x != 0) || (T[jj4 + 0][ii] != 0)) ? 1 : 0;
    o.y = ((m1.y != 0) || (T[jj4 + 1][ii] != 0)) ? 1 : 0;
    o.z = ((m1.z != 0) || (T[jj4 + 2][ii] != 0)) ? 1 : 0;
    o.w = ((m1.w != 0) || (T[jj4 + 3][ii] != 0)) ? 1 : 0;
    *(uchar4*)&msym[bO + (size_t)(i0 + ii) * S_ + j0 + jj4] = o;
  } else if (blk < 6144) {
    const size_t i = ((size_t)(blk - 4096) * 256 + tid) * 8;
    const float4 a = *(const float4*)(x + i);
    const float4 b = *(const float4*)(x + i + 4);
    const ushort4 p0 = {f2bf(a.x), f2bf(a.y), f2bf(a.z), f2bf(a.w)};
    const ushort4 p1 = {f2bf(b.x), f2bf(b.y), f2bf(b.z), f2bf(b.w)};
    *(ushort4*)(xbf + i) = p0;
    *(ushort4*)(xbf + i + 4) = p1;
  } else {
    unsigned short (*T2)[36] = (unsigned short(*)[36])u_lds;
    const int wblk = blk - 6144;           // 2 * 32 * 32
    const int mat = wblk >> 10;
    const int kt = (wblk >> 5) & 31, ntb = wblk & 31;
    const float* W = mat ? Wk : Wq;
    const int r = tid >> 3, c4 = (tid & 7) << 2;
    const float4 v = *(const float4*)&W[(size_t)(kt * 32 + r) * 1024 + ntb * 32 + c4];
    T2[r][c4 + 0] = f2bf(v.x); T2[r][c4 + 1] = f2bf(v.y);
    T2[r][c4 + 2] = f2bf(v.z); T2[r][c4 + 3] = f2bf(v.w);
    __syncthreads();
    const ushort4 o = {T2[c4 + 0][r], T2[c4 + 1][r], T2[c4 + 2][r], T2[c4 + 3][r]};
    *(ushort4*)&Wt[(size_t)(mat * 1024 + ntb * 32 + r) * 1024 + kt * 32 + c4] = o;
  }
}

// ------- bf16 MFMA GEMM: P[4096][nstride] = xbf[4096][1024] @ Wt^T (Wt is [n][k]) -----
__global__ __launch_bounds__(256) void gemm_mfma_kernel(const unsigned short* __restrict__ Abf,
                                                        const unsigned short* __restrict__ Wt,
                                                        unsigned short* __restrict__ P,
                                                        int nstride) {
  __shared__ __align__(16) unsigned short As[128 * 32];
  __shared__ __align__(16) unsigned short Bs[128 * 32];
  const int tid = threadIdx.x;
  const int m0 = (blockIdx.x & 31) << 7;
  const int n0 = (blockIdx.x >> 5) << 7;
  const int wave = tid >> 6, lane = tid & 63;
  const int ln15 = lane & 15, rg = lane >> 4;
  const int wm = (wave & 1) << 6;
  const int wn = (wave >> 1) << 6;
  const int sr = tid >> 2;
  const int sc = (tid & 3) << 3;
  const unsigned short* gA = Abf + (size_t)(m0 + sr) * 1024 + sc;
  const unsigned short* gB = Wt + (size_t)(n0 + sr) * 1024 + sc;
  unsigned short* lA = As + tid * 8;
  unsigned short* lB = Bs + tid * 8;
  f32x4 acc[4][4];
#pragma unroll
  for (int i = 0; i < 4; ++i)
#pragma unroll
    for (int j = 0; j < 4; ++j) acc[i][j] = (f32x4){0.0f, 0.0f, 0.0f, 0.0f};

  const unsigned short* pa = As + (wm + ln15) * 32 + rg * 8;
  const unsigned short* pb = Bs + (wn + ln15) * 32 + rg * 8;
  for (int k0 = 0; k0 < E_; k0 += 32) {
    GL2LDS16(gA + k0, lA);
    GL2LDS16(gA + k0 + (size_t)64 * 1024, lA + 2048);
    GL2LDS16(gB + k0, lB);
    GL2LDS16(gB + k0 + (size_t)64 * 1024, lB + 2048);
    __syncthreads();
    short8 af[4], bfr[4];
#pragma unroll
    for (int i = 0; i < 4; ++i) af[i] = *(const short8*)(pa + i * 16 * 32);
#pragma unroll
    for (int j = 0; j < 4; ++j) bfr[j] = *(const short8*)(pb + j * 16 * 32);
#pragma unroll
    for (int i = 0; i < 4; ++i)
#pragma unroll
      for (int j = 0; j < 4; ++j)
        acc[i][j] = __builtin_amdgcn_mfma_f32_16x16x32_bf16(af[i], bfr[j], acc[i][j], 0, 0, 0);
    __syncthreads();
  }
#pragma unroll
  for (int i = 0; i < 4; ++i)
#pragma unroll
    for (int j = 0; j < 4; ++j)
#pragma unroll
      for (int r = 0; r < 4; ++r) {
        const int row = m0 + wm + i * 16 + rg * 4 + r;
        const int col = n0 + wn + j * 16 + ln15;
        P[(size_t)row * nstride + col] = f2bf(acc[i][j][r]);
      }
}

// ---- bias+LN+ReLU from bf16 P; oscale folds the 1/sqrt(D) into Q (exact in bf16) ----
__device__ __forceinline__ void ln_body(const unsigned short* p, const float* bias,
                                        const float* gamma, const float* beta,
                                        unsigned short* obf, int b, int s, int tid,
                                        float oscale) {
  const ushort4 pv = *(const ushort4*)(p + tid * 4);
  float4 v = {bf2f(pv.x), bf2f(pv.y), bf2f(pv.z), bf2f(pv.w)};
  const float4 bb = ((const float4*)bias)[tid];
  v.x += bb.x; v.y += bb.y; v.z += bb.z; v.w += bb.w;
  float sum = v.x + v.y + v.z + v.w;
  float s2 = v.x * v.x + v.y * v.y + v.z * v.z + v.w * v.w;
#pragma unroll
  for (int off = 32; off >= 1; off >>= 1) {
    sum += __shfl_xor(sum, off);
    s2 += __shfl_xor(s2, off);
  }
  __shared__ float red[2][4];
  const int wave = tid >> 6, lane = tid & 63;
  if (lane == 0) { red[0][wave] = sum; red[1][wave] = s2; }
  __syncthreads();
  sum = red[0][0] + red[0][1] + red[0][2] + red[0][3];
  s2 = red[1][0] + red[1][1] + red[1][2] + red[1][3];
  const float mu = sum * (1.0f / E_);
  const float var = s2 * (1.0f / E_) - mu * mu;
  const float r = rsqrtf(var + 1e-5f);
  const float4 g = ((const float4*)gamma)[tid];
  const float4 bt = ((const float4*)beta)[tid];
  const float o0 = fmaxf((v.x - mu) * r * g.x + bt.x, 0.0f) * oscale;
  const float o1 = fmaxf((v.y - mu) * r * g.y + bt.y, 0.0f) * oscale;
  const float o2 = fmaxf((v.z - mu) * r * g.z + bt.z, 0.0f) * oscale;
  const float o3 = fmaxf((v.w - mu) * r * g.w + bt.w, 0.0f) * oscale;
  const int h = tid >> 4;
  const int d = (tid & 15) << 2;
  const ushort4 ob = {f2bf(o0), f2bf(o1), f2bf(o2), f2bf(o3)};
  *(ushort4*)&obf[((size_t)(b * H_ + h) * S_ + s) * D_ + d] = ob;
}

__global__ __launch_bounds__(256) void ln_relu_bf_kernel(const unsigned short* __restrict__ P,
                                                         int rowstride, int coloff,
                                                         const float* __restrict__ bias,
                                                         const float* __restrict__ gamma,
                                                         const float* __restrict__ beta,
                                                         unsigned short* __restrict__ obf,
                                                         float oscale) {
  const int row = blockIdx.x;
  ln_body(P + (size_t)row * rowstride + coloff, bias, gamma, beta, obf,
          row >> 10, row & 1023, threadIdx.x, oscale);
}

// fused both-LN launch (40MB path): blocks 0..4095 -> Q (scaled by 0.125), 4096..8191 -> K
__global__ __launch_bounds__(256) void ln2_kernel(const unsigned short* __restrict__ P2,
                                                  const float* __restrict__ bq,
                                                  const float* __restrict__ gq,
                                                  const float* __restrict__ bqn,
                                                  const float* __restrict__ bk,
                                                  const float* __restrict__ gk,
                                                  const float* __restrict__ bkn,
                                                  unsigned short* __restrict__ Qbf,
                                                  unsigned short* __restrict__ Kbf) {
  const int blk = blockIdx.x;
  const int sel = blk >> 12;
  const int row = blk & 4095;
  ln_body(P2 + (size_t)row * 2048 + sel * 1024,
          sel ? bk : bq, sel ? gk : gq, sel ? bkn : bqn,
          sel ? Kbf : Qbf, row >> 10, row & 1023, threadIdx.x,
          sel ? 1.0f : 0.125f);
}

// ======= attention v7: q-split (8 rows/block), 16 heads in-block, no atomics =======
// grid 512: b = blk&3 (XCD j hosts b=j&3 -> K[b] 2MB L2-resident), qt = blk>>2 (128
// 8-row q tiles). 512 thr = 8 waves, 2 blocks/CU co-resident (LDS 48.5 KB, VGPR<=128).
// MFMA 16-row tile carries 8 valid q rows (rows 8-15 duplicated, masked): 2x MFMA
// waste at 5% util = free; output rows disjoint -> plain stores; l block-local.
// K pipeline: 2 tiles in flight in registers -- tile s+2 issued at top of step s,
// committed to LDS at end of step s+1 -> issue-to-wait ~1.5 steps > L2 latency.
// LDS XOR chunk swizzle (p = c ^ (row&7)) for conflict-free b128 reads/writes.
// MFMA 16x16x32 bf16, C-layout: col(key)=lane&15, row(q)=(lane>>4)*4+reg.
__global__ __launch_bounds__(512, 4) void attn7_kernel(const unsigned short* __restrict__ Qbf,
                                                       const unsigned short* __restrict__ Kbf,
                                                       const unsigned char* __restrict__ msym,
                                                       float* __restrict__ out) {
  __shared__ __align__(16) unsigned short Qs[128 * 64];     // 16 KB: row = h*8 + q(0..7)
  __shared__ __align__(16) unsigned short Ks[2][128 * 64];  // 32 KB: row = key-in-tile
  __shared__ __align__(16) float l_lds[16][8];              // [q16][wave]
  const int tid = threadIdx.x;
  const int wave = tid >> 6, lane = tid & 63;
  const int ln15 = lane & 15, rg = lane >> 4;
  const int b = blockIdx.x & 3;
  const int q0 = (blockIdx.x >> 2) << 3;                    // 8-row q tile
  const unsigned short* Kb = Kbf + (size_t)b * H_ * S_ * D_;

  // stage Q: 16 heads x 8 q x 64 d, XOR-swizzled chunks
  {
    const int rho = tid >> 2;          // 0..127 = h*8 + q
    const int c0 = (tid & 3) << 1;     // logical chunks c0, c0+1
    const int x = rho & 7;
    const unsigned short* src =
        Qbf + ((size_t)(b * H_ + (rho >> 3)) * S_ + q0 + (rho & 7)) * D_ + c0 * 8;
    const uint4 v0 = *(const uint4*)src;
    const uint4 v1 = *(const uint4*)(src + 8);
    *(uint4*)&Qs[rho * 64 + (c0 ^ x) * 8] = v0;
    *(uint4*)&Qs[rho * 64 + ((c0 + 1) ^ x) * 8] = v1;
  }
  // K staging thread map
  const int krow = tid >> 2, kc0 = (tid & 3) << 1;
  const int kx = krow & 7;
  const int kp0 = (kc0 ^ kx) * 8, kp1 = ((kc0 + 1) ^ kx) * 8;
  // mask bits: rows rg*4+r valid only for rg<2; others forced masked
  unsigned int mbits = 0xFFFFFFFFu;
  if (rg < 2) {
    mbits = 0;
#pragma unroll
    for (int t = 0; t < 8; ++t)
#pragma unroll
      for (int r = 0; r < 4; ++r)
        mbits |= (msym[((size_t)b * S_ + q0 + rg * 4 + r) * S_ + t * 128 + wave * 16 + ln15] ? 1u : 0u)
                 << (t * 4 + r);
  }
  // prologue: issue tiles 0 and 1 into registers; commit tile 0
  uint4 pf[2][2];
  {
    const unsigned short* src0 = Kb + (size_t)krow * D_ + kc0 * 8;
    pf[0][0] = *(const uint4*)src0;
    pf[0][1] = *(const uint4*)(src0 + 8);
    const unsigned short* src1 = src0 + (size_t)128 * D_;
    pf[1][0] = *(const uint4*)src1;
    pf[1][1] = *(const uint4*)(src1 + 8);
    *(uint4*)&Ks[0][krow * 64 + kp0] = pf[0][0];
    *(uint4*)&Ks[0][krow * 64 + kp1] = pf[0][1];
  }
  __syncthreads();

  const int pfrag = (rg ^ (ln15 & 7)) * 8;  // swizzled chunk offset (shorts)
  float o[8][4] = {};

#pragma unroll 1
  for (int hl = 0; hl < 16; ++hl) {
    const unsigned short* qrow = Qs + ((hl << 3) + (ln15 & 7)) * 64;  // rows 8-15 duplicate 0-7
    const short8 a0 = *(const short8*)(qrow + pfrag);
    const short8 a1 = *(const short8*)(qrow + (pfrag ^ 32));
    float la[4] = {0.0f, 0.0f, 0.0f, 0.0f};
    unsigned int epack[8][2];
#pragma unroll
    for (int t = 0; t < 8; ++t) {
      // issue tile s+2 (s = hl*8+t) into pf[t&1] (freed by commit at end of step s-1)
      if (hl < 15 || t < 6) {
        const int s2 = hl * 8 + t + 2;
        const unsigned short* src =
            Kb + ((size_t)(s2 >> 3) * S_ + ((s2 & 7) << 7) + krow) * D_ + kc0 * 8;
        pf[t & 1][0] = *(const uint4*)src;
        pf[t & 1][1] = *(const uint4*)(src + 8);
      }
      // compute tile t from Ks[t&1]
      const unsigned short* kw = Ks[t & 1] + (wave * 16 + ln15) * 64;
      const short8 b0 = *(const short8*)(kw + pfrag);
      const short8 b1 = *(const short8*)(kw + (pfrag ^ 32));
      f32x4 cc = {0.0f, 0.0f, 0.0f, 0.0f};
      cc = __builtin_amdgcn_mfma_f32_16x16x32_bf16(a0, b0, cc, 0, 0, 0);
      cc = __builtin_amdgcn_mfma_f32_16x16x32_bf16(a1, b1, cc, 0, 0, 0);
      float e[4];
#pragma unroll
      for (int r = 0; r < 4; ++r) {
        const float sv = fminf(cc[r], 80.0f);   // scale pre-folded into Q
        e[r] = ((mbits >> (t * 4 + r)) & 1u) ? 0.0f : __expf(sv);
        la[r] += e[r];
      }
      epack[t][0] = (unsigned)f2bf(e[0]) | ((unsigned)f2bf(e[1]) << 16);
      epack[t][1] = (unsigned)f2bf(e[2]) | ((unsigned)f2bf(e[3]) << 16);
      if (t == 7) {  // head end: 16-lane reduce + publish before the shared barrier
#pragma unroll
        for (int r = 0; r < 4; ++r) {
          float lv = la[r];
          lv += __shfl_xor(lv, 1);
          lv += __shfl_xor(lv, 2);
          lv += __shfl_xor(lv, 4);
          lv += __shfl_xor(lv, 8);
          la[r] = lv;
        }
        if (ln15 == 0) {
#pragma unroll
          for (int r = 0; r < 4; ++r) l_lds[rg * 4 + r][wave] = la[r];
        }
      }
      // commit tile s+1 (issued a full step ago) to the other buffer
      if (hl < 15 || t < 7) {
        unsigned short* dst = Ks[(t + 1) & 1];
        *(uint4*)&dst[krow * 64 + kp0] = pf[(t + 1) & 1][0];
        *(uint4*)&dst[krow * 64 + kp1] = pf[(t + 1) & 1][1];
      }
      __syncthreads();
    }
    // after the head's last barrier: lane-local linv + scale into o
#pragma unroll
    for (int r = 0; r < 4; ++r) {
      const float4 va = *(const float4*)&l_lds[rg * 4 + r][0];
      const float4 vb = *(const float4*)&l_lds[rg * 4 + r][4];
      const float ssum = ((va.x + va.y) + (va.z + va.w)) + ((vb.x + vb.y) + (vb.z + vb.w));
      const float li = 0.0625f * __builtin_amdgcn_rcpf(ssum);
#pragma unroll
      for (int t = 0; t < 8; ++t) {
        const unsigned u = epack[t][r >> 1];
        const float ev = (r & 1) ? __uint_as_float(u & 0xFFFF0000u) : __uint_as_float(u << 16);
        o[t][r] += ev * li;
      }
    }
  }
  // plain stores: rows disjoint across blocks (q-split)
  if (rg < 2) {
#pragma unroll
    for (int t = 0; t < 8; ++t)
#pragma unroll
      for (int r = 0; r < 4; ++r)
        out[((size_t)b * S_ + q0 + rg * 4 + r) * S_ + t * 128 + wave * 16 + ln15] = o[t][r];
  }
}

extern "C" void kernel_launch(void* const* d_in, const int* in_sizes, int n_in,
                              void* d_out, int out_size, void* d_ws, size_t ws_size,
                              hipStream_t stream) {
  const float* x = (const float*)d_in[0];
  const int* mask = (const int*)d_in[1];
  const float* Wq = (const float*)d_in[2];
  const float* bq = (const float*)d_in[3];
  const float* Wk = (const float*)d_in[4];
  const float* bk = (const float*)d_in[5];
  const float* gq = (const float*)d_in[6];
  const float* bq_n = (const float*)d_in[7];
  const float* gk = (const float*)d_in[8];
  const float* bk_n = (const float*)d_in[9];
  float* out = (float*)d_out;

  char* ws = (char*)d_ws;
  const size_t MB = 1024 * 1024;

  if (ws_size >= 40 * MB) {
    // fused layout (40 MB): P2 bf16 [4096][2048] @0 (16), xbf @16 (8, Kbf aliases),
    // Wt @24 (4), Qbf @28 (8), msym @36 (4)
    unsigned short* P2 = (unsigned short*)ws;
    unsigned short* xbf = (unsigned short*)(ws + 16 * MB);
    unsigned short* Kbf = (unsigned short*)(ws + 16 * MB);   // alias: xbf dead after gemm
    unsigned short* Wt = (unsigned short*)(ws + 24 * MB);
    unsigned short* Qbf = (unsigned short*)(ws + 28 * MB);
    unsigned char* msym = (unsigned char*)(ws + 36 * MB);

    prep_kernel<<<8192, 256, 0, stream>>>(mask, x, Wq, Wk, msym, xbf, Wt);
    gemm_mfma_kernel<<<512, 256, 0, stream>>>(xbf, Wt, P2, 2048);
    ln2_kernel<<<8192, 256, 0, stream>>>(P2, bq, gq, bq_n, bk, gk, bk_n, Qbf, Kbf);
    attn7_kernel<<<512, 512, 0, stream>>>(Qbf, Kbf, msym, out);
  } else {
    // split layout (32 MB): P bf16 [4096][1024] @0 (8), xbf @8 (8, Kbf aliases),
    // Wt @16 (4), Qbf @20 (8), msym @28 (4)
    unsigned short* P = (unsigned short*)ws;
    unsigned short* xbf = (unsigned short*)(ws + 8 * MB);
    unsigned short* Kbf = (unsigned short*)(ws + 8 * MB);    // alias: xbf dead after 2nd gemm
    unsigned short* Wt = (unsigned short*)(ws + 16 * MB);
    unsigned short* Qbf = (unsigned short*)(ws + 20 * MB);
    unsigned char* msym = (unsigned char*)(ws + 28 * MB);

    prep_kernel<<<8192, 256, 0, stream>>>(mask, x, Wq, Wk, msym, xbf, Wt);
    gemm_mfma_kernel<<<256, 256, 0, stream>>>(xbf, Wt, P, 1024);
    ln_relu_bf_kernel<<<4096, 256, 0, stream>>>(P, 1024, 0, bq, gq, bq_n, Qbf, 0.125f);
    gemm_mfma_kernel<<<256, 256, 0, stream>>>(xbf, Wt + (size_t)1024 * 1024, P, 1024);
    ln_relu_bf_kernel<<<4096, 256, 0, stream>>>(P, 1024, 0, bk, gk, bk_n, Kbf, 1.0f);
    attn7_kernel<<<512, 512, 0, stream>>>(Qbf, Kbf, msym, out);
  }
}

// Round 10
// 199.082 us; speedup vs baseline: 2.0771x; 2.0771x over previous
//
#include <hip/hip_runtime.h>
#include <hip/hip_bf16.h>

#define B_ 4
#define S_ 1024
#define E_ 1024
#define H_ 16
#define D_ 64

typedef __attribute__((ext_vector_type(8))) short short8;
typedef __attribute__((ext_vector_type(4))) float f32x4;

static __device__ __forceinline__ unsigned short f2bf(float x) {
  unsigned int u = __float_as_uint(x);
  unsigned int r = u + 0x7fffu + ((u >> 16) & 1u);  // round-to-nearest-even
  return (unsigned short)(r >> 16);
}
static __device__ __forceinline__ float bf2f(unsigned short b) {
  return __uint_as_float((unsigned int)b << 16);
}

#define GL2LDS16(g, l)                                                            \
  __builtin_amdgcn_global_load_lds(                                               \
      (const __attribute__((address_space(1))) unsigned int*)(g),                 \
      (__attribute__((address_space(3))) unsigned int*)(l), 16, 0, 0)

// ---------- fused preprocessing: mask|mask^T, x->bf16, W->Wt bf16 ----------
// blocks 0..4095: mask_sym; 4096..6143: cvt_x; 6144..8191: wt transpose
__global__ __launch_bounds__(256) void prep_kernel(const int* __restrict__ mask,
                                                   const float* __restrict__ x,
                                                   const float* __restrict__ Wq,
                                                   const float* __restrict__ Wk,
                                                   unsigned char* __restrict__ msym,
                                                   unsigned short* __restrict__ xbf,
                                                   unsigned short* __restrict__ Wt) {
  __shared__ __align__(16) char u_lds[32 * 33 * 4];
  const int blk = blockIdx.x;
  const int tid = threadIdx.x;
  if (blk < 4096) {
    int (*T)[33] = (int(*)[33])u_lds;
    const int b = blk >> 10;
    const int rest = blk & 1023;
    const int i0 = (rest >> 5) << 5;
    const int j0 = (rest & 31) << 5;
    const int ii = tid >> 3;
    const int jj4 = (tid & 7) << 2;
    const size_t bO = (size_t)b * S_ * S_;
    const int4 m2 = *(const int4*)&mask[bO + (size_t)(j0 + ii) * S_ + i0 + jj4];
    T[ii][jj4 + 0] = m2.x; T[ii][jj4 + 1] = m2.y; T[ii][jj4 + 2] = m2.z; T[ii][jj4 + 3] = m2.w;
    __syncthreads();
    const int4 m1 = *(const int4*)&mask[bO + (size_t)(i0 + ii) * S_ + j0 + jj4];
    uchar4 o;
    o.x = ((m1.x != 0) || (T[jj4 + 0][ii] != 0)) ? 1 : 0;
    o.y = ((m1.y != 0) || (T[jj4 + 1][ii] != 0)) ? 1 : 0;
    o.z = ((m1.z != 0) || (T[jj4 + 2][ii] != 0)) ? 1 : 0;
    o.w = ((m1.w != 0) || (T[jj4 + 3][ii] != 0)) ? 1 : 0;
    *(uchar4*)&msym[bO + (size_t)(i0 + ii) * S_ + j0 + jj4] = o;
  } else if (blk < 6144) {
    const size_t i = ((size_t)(blk - 4096) * 256 + tid) * 8;
    const float4 a = *(const float4*)(x + i);
    const float4 b = *(const float4*)(x + i + 4);
    const ushort4 p0 = {f2bf(a.x), f2bf(a.y), f2bf(a.z), f2bf(a.w)};
    const ushort4 p1 = {f2bf(b.x), f2bf(b.y), f2bf(b.z), f2bf(b.w)};
    *(ushort4*)(xbf + i) = p0;
    *(ushort4*)(xbf + i + 4) = p1;
  } else {
    unsigned short (*T2)[36] = (unsigned short(*)[36])u_lds;
    const int wblk = blk - 6144;           // 2 * 32 * 32
    const int mat = wblk >> 10;
    const int kt = (wblk >> 5) & 31, ntb = wblk & 31;
    const float* W = mat ? Wk : Wq;
    const int r = tid >> 3, c4 = (tid & 7) << 2;
    const float4 v = *(const float4*)&W[(size_t)(kt * 32 + r) * 1024 + ntb * 32 + c4];
    T2[r][c4 + 0] = f2bf(v.x); T2[r][c4 + 1] = f2bf(v.y);
    T2[r][c4 + 2] = f2bf(v.z); T2[r][c4 + 3] = f2bf(v.w);
    __syncthreads();
    const ushort4 o = {T2[c4 + 0][r], T2[c4 + 1][r], T2[c4 + 2][r], T2[c4 + 3][r]};
    *(ushort4*)&Wt[(size_t)(mat * 1024 + ntb * 32 + r) * 1024 + kt * 32 + c4] = o;
  }
}

// ------- bf16 MFMA GEMM, BK=64: P[4096][nstride] = xbf[4096][1024] @ Wt^T --------
// 128x128 tile, 16 K-iters (32 barriers vs 64 at BK=32), 32 MFMA/iter.
// Staging: 4 global_load_lds(16B) per operand per iter; wave-uniform base + lane*16.
__global__ __launch_bounds__(256) void gemm_mfma_kernel(const unsigned short* __restrict__ Abf,
                                                        const unsigned short* __restrict__ Wt,
                                                        unsigned short* __restrict__ P,
                                                        int nstride) {
  __shared__ __align__(16) unsigned short As[128 * 64];  // 16 KB, [m][k]
  __shared__ __align__(16) unsigned short Bs[128 * 64];  // 16 KB, [n][k]
  const int tid = threadIdx.x;
  const int m0 = (blockIdx.x & 31) << 7;
  const int n0 = (blockIdx.x >> 5) << 7;
  const int wave = tid >> 6, lane = tid & 63;
  const int ln15 = lane & 15, rg = lane >> 4;
  const int wm = (wave & 1) << 6;
  const int wn = (wave >> 1) << 6;
  // staging map: call j covers rows j*32 + (tid>>3), cols (tid&7)*8 .. +7
  const int sr = tid >> 3;
  const int sc = (tid & 7) << 3;
  const unsigned short* gA = Abf + (size_t)(m0 + sr) * 1024 + sc;
  const unsigned short* gB = Wt + (size_t)(n0 + sr) * 1024 + sc;
  unsigned short* lA = As + tid * 8;   // = tid*16 B, lane-contiguous per wave
  unsigned short* lB = Bs + tid * 8;
  f32x4 acc[4][4];
#pragma unroll
  for (int i = 0; i < 4; ++i)
#pragma unroll
    for (int j = 0; j < 4; ++j) acc[i][j] = (f32x4){0.0f, 0.0f, 0.0f, 0.0f};

  const unsigned short* pa = As + (wm + ln15) * 64 + rg * 8;
  const unsigned short* pb = Bs + (wn + ln15) * 64 + rg * 8;
  for (int k0 = 0; k0 < E_; k0 += 64) {
#pragma unroll
    for (int j = 0; j < 4; ++j) {
      GL2LDS16(gA + k0 + (size_t)(j * 32) * 1024, lA + j * 2048);
      GL2LDS16(gB + k0 + (size_t)(j * 32) * 1024, lB + j * 2048);
    }
    __syncthreads();
#pragma unroll
    for (int kk = 0; kk < 2; ++kk) {
      short8 af[4], bfr[4];
#pragma unroll
      for (int i = 0; i < 4; ++i) af[i] = *(const short8*)(pa + i * 16 * 64 + kk * 32);
#pragma unroll
      for (int j = 0; j < 4; ++j) bfr[j] = *(const short8*)(pb + j * 16 * 64 + kk * 32);
#pragma unroll
      for (int i = 0; i < 4; ++i)
#pragma unroll
        for (int j = 0; j < 4; ++j)
          acc[i][j] = __builtin_amdgcn_mfma_f32_16x16x32_bf16(af[i], bfr[j], acc[i][j], 0, 0, 0);
    }
    __syncthreads();
  }
#pragma unroll
  for (int i = 0; i < 4; ++i)
#pragma unroll
    for (int j = 0; j < 4; ++j)
#pragma unroll
      for (int r = 0; r < 4; ++r) {
        const int row = m0 + wm + i * 16 + rg * 4 + r;
        const int col = n0 + wn + j * 16 + ln15;
        P[(size_t)row * nstride + col] = f2bf(acc[i][j][r]);
      }
}

// ------- bias + LayerNorm + ReLU from bf16 P; emit bf16 head-major [b*16+h][s][d] -------
__global__ __launch_bounds__(256) void ln_relu_bf_kernel(const unsigned short* __restrict__ P,
                                                         int rowstride, int coloff,
                                                         const float* __restrict__ bias,
                                                         const float* __restrict__ gamma,
                                                         const float* __restrict__ beta,
                                                         unsigned short* __restrict__ obf) {
  const int row = blockIdx.x;
  const int b = row >> 10, s = row & 1023;
  const unsigned short* p = P + (size_t)row * rowstride + coloff;
  const int tid = threadIdx.x;
  const ushort4 pv = *(const ushort4*)(p + tid * 4);
  float4 v = {bf2f(pv.x), bf2f(pv.y), bf2f(pv.z), bf2f(pv.w)};
  const float4 bb = ((const float4*)bias)[tid];
  v.x += bb.x; v.y += bb.y; v.z += bb.z; v.w += bb.w;
  float sum = v.x + v.y + v.z + v.w;
  float s2 = v.x * v.x + v.y * v.y + v.z * v.z + v.w * v.w;
#pragma unroll
  for (int off = 32; off >= 1; off >>= 1) {
    sum += __shfl_xor(sum, off);
    s2 += __shfl_xor(s2, off);
  }
  __shared__ float red[2][4];
  const int wave = tid >> 6, lane = tid & 63;
  if (lane == 0) { red[0][wave] = sum; red[1][wave] = s2; }
  __syncthreads();
  sum = red[0][0] + red[0][1] + red[0][2] + red[0][3];
  s2 = red[1][0] + red[1][1] + red[1][2] + red[1][3];
  const float mu = sum * (1.0f / E_);
  const float var = s2 * (1.0f / E_) - mu * mu;
  const float r = rsqrtf(var + 1e-5f);
  const float4 g = ((const float4*)gamma)[tid];
  const float4 bt = ((const float4*)beta)[tid];
  const float o0 = fmaxf((v.x - mu) * r * g.x + bt.x, 0.0f);
  const float o1 = fmaxf((v.y - mu) * r * g.y + bt.y, 0.0f);
  const float o2 = fmaxf((v.z - mu) * r * g.z + bt.z, 0.0f);
  const float o3 = fmaxf((v.w - mu) * r * g.w + bt.w, 0.0f);
  const int h = tid >> 4;
  const int d = (tid & 15) << 2;
  const ushort4 ob = {f2bf(o0), f2bf(o1), f2bf(o2), f2bf(o3)};
  *(ushort4*)&obf[((size_t)(b * H_ + h) * S_ + s) * D_ + d] = ob;
}

// ======= fused attention: head-outer, double-buffered LDS K staging (r7-proven) =======
// block: (b, 16-q), grid 256, 1024 thr = 16 waves. Per head: 4 quarter-tiles of 256
// keys staged cooperatively in LDS (double-buffered, register prefetch overlaps
// compute). e stored fp32 in regs (16 VGPRs/head; no bf16 pack/unpack VALU).
// LDS layout: row stride 128 B, chunk XOR-swizzle p = c ^ (row&7).
// MFMA 16x16x32 bf16, C-layout: col(key)=lane&15, row(q)=(lane>>4)*4+reg.
__global__ __launch_bounds__(1024, 4) void attn5_kernel(const unsigned short* __restrict__ Qbf,
                                                        const unsigned short* __restrict__ Kbf,
                                                        const unsigned char* __restrict__ msym,
                                                        float* __restrict__ out) {
  __shared__ __align__(16) unsigned short Qs[256 * 64];     // 32 KB: row = h*16+q
  __shared__ __align__(16) unsigned short Ks[2][256 * 64];  // 64 KB: row = key-in-quarter
  __shared__ __align__(16) float l_lds[16][16];             // [wave][q]
  __shared__ __align__(16) float linv[16];
  const int tid = threadIdx.x;
  const int wave = tid >> 6, lane = tid & 63;
  const int ln15 = lane & 15, rg = lane >> 4;
  const int b = blockIdx.x & 3;                 // XCD swizzle
  const int q0 = (blockIdx.x >> 2) << 4;

  const unsigned short* Kb = Kbf + (size_t)b * H_ * S_ * D_;

  // ---- stage Q[h=0..15][q=0..15][64] (32 KB), swizzled ----
  {
    const int rho = tid >> 3, p = tid & 7;
    const int c = p ^ (rho & 7);
    const int rho2 = rho + 128;
    const int c2 = p ^ (rho2 & 7);  // == c (rho2&7 == rho&7)
    const uint4 v0 = *(const uint4*)(Qbf + ((size_t)(b * H_ + (rho >> 4)) * S_ + q0 + (rho & 15)) * D_ + c * 8);
    const uint4 v1 = *(const uint4*)(Qbf + ((size_t)(b * H_ + (rho2 >> 4)) * S_ + q0 + (rho2 & 15)) * D_ + c2 * 8);
    *(uint4*)&Qs[rho * 64 + p * 8] = v0;
    *(uint4*)&Qs[rho2 * 64 + p * 8] = v1;
  }
  // ---- mask bits: bit(qt*4+r) = msym[q0+rg*4+r][qt*256 + wave*16 + ln15] ----
  unsigned int mbits = 0;
#pragma unroll
  for (int qt = 0; qt < 4; ++qt)
#pragma unroll
    for (int r = 0; r < 4; ++r)
      mbits |= (msym[((size_t)b * S_ + q0 + rg * 4 + r) * S_ + qt * 256 + wave * 16 + ln15] ? 1u : 0u)
               << (qt * 4 + r);

  // ---- staging thread mapping: key rows krow, krow+128; phys chunk kp ----
  const int krow = tid >> 3, kp = tid & 7;
  const int kcc = kp ^ (krow & 7);              // logical chunk for both rows
  // prologue: stage step 0 (h=0, qt=0) into Ks[0]
  {
    const unsigned short* src = Kb + (size_t)krow * D_ + kcc * 8;
    const uint4 p0 = *(const uint4*)src;
    const uint4 p1 = *(const uint4*)(src + 128 * D_);
    *(uint4*)&Ks[0][krow * 64 + kp * 8] = p0;
    *(uint4*)&Ks[0][(krow + 128) * 64 + kp * 8] = p1;
  }
  __syncthreads();

  const int pfrag = (rg ^ (ln15 & 7)) * 8;      // swizzled chunk offset (shorts)
  const unsigned short* QsW = Qs + ln15 * 64;
  const unsigned short* KsW0 = Ks[0] + (wave * 16 + ln15) * 64;
  const unsigned short* KsW1 = Ks[1] + (wave * 16 + ln15) * 64;

  float o[4][4] = {};
  float ef[4][4];
  uint4 pf0, pf1;

#pragma unroll 1
  for (int h = 0; h < 16; ++h) {
    const unsigned short* qrow = QsW + h * 16 * 64;
    const short8 a0 = *(const short8*)(qrow + pfrag);
    const short8 a1 = *(const short8*)(qrow + (pfrag ^ 32));
    float la[4] = {0.0f, 0.0f, 0.0f, 0.0f};
#pragma unroll
    for (int qt = 0; qt < 4; ++qt) {
      const int s = h * 4 + qt;
      // prefetch step s+1 into registers (latency overlapped by this step's compute)
      if (s < 63) {
        const int s1 = s + 1;
        const unsigned short* src =
            Kb + ((size_t)(s1 >> 2) * S_ + ((s1 & 3) << 8) + krow) * D_ + kcc * 8;
        pf0 = *(const uint4*)src;
        pf1 = *(const uint4*)(src + 128 * D_);
      }
      // compute from current buffer (buf = qt&1 since h*4 is even)
      const unsigned short* kw = (qt & 1) ? KsW1 : KsW0;
      const short8 b0 = *(const short8*)(kw + pfrag);
      const short8 b1 = *(const short8*)(kw + (pfrag ^ 32));
      f32x4 cc = {0.0f, 0.0f, 0.0f, 0.0f};
      cc = __builtin_amdgcn_mfma_f32_16x16x32_bf16(a0, b0, cc, 0, 0, 0);
      cc = __builtin_amdgcn_mfma_f32_16x16x32_bf16(a1, b1, cc, 0, 0, 0);
#pragma unroll
      for (int r = 0; r < 4; ++r) {
        const float sv = fminf(cc[r] * 0.125f, 80.0f);
        const float ev = ((mbits >> (qt * 4 + r)) & 1u) ? 0.0f : __expf(sv);
        ef[qt][r] = ev;
        la[r] += ev;
      }
      // commit prefetched tile to the other buffer
      if (s < 63) {
        unsigned short* dst = (qt & 1) ? Ks[0] : Ks[1];
        *(uint4*)&dst[krow * 64 + kp * 8] = pf0;
        *(uint4*)&dst[(krow + 128) * 64 + kp * 8] = pf1;
      }
      if (qt < 3) __syncthreads();
    }
    // head end: reduce l over the 16 key-lanes per q-row, then cross-wave
#pragma unroll
    for (int r = 0; r < 4; ++r) {
      float lv = la[r];
      lv += __shfl_xor(lv, 1);
      lv += __shfl_xor(lv, 2);
      lv += __shfl_xor(lv, 4);
      lv += __shfl_xor(lv, 8);
      la[r] = lv;
    }
    if (ln15 == 0) *(float4*)&l_lds[wave][rg * 4] = (float4){la[0], la[1], la[2], la[3]};
    __syncthreads();   // covers l_lds + next head's K buffer
    if (tid < 16) {
      float ssum = 0.0f;
#pragma unroll
      for (int w = 0; w < 16; ++w) ssum += l_lds[w][tid];
      linv[tid] = 0.0625f / ssum;   // 1/(16*l): head-mean folded in
    }
    __syncthreads();
    const float4 li4 = *(const float4*)&linv[rg * 4];
#pragma unroll
    for (int qt = 0; qt < 4; ++qt) {
      o[qt][0] += ef[qt][0] * li4.x;
      o[qt][1] += ef[qt][1] * li4.y;
      o[qt][2] += ef[qt][2] * li4.z;
      o[qt][3] += ef[qt][3] * li4.w;
    }
  }
  // direct stores: each 16-lane group writes 64 B contiguous per (qt,r)
#pragma unroll
  for (int qt = 0; qt < 4; ++qt)
#pragma unroll
    for (int r = 0; r < 4; ++r)
      out[((size_t)b * S_ + q0 + rg * 4 + r) * S_ + qt * 256 + wave * 16 + ln15] = o[qt][r];
}

extern "C" void kernel_launch(void* const* d_in, const int* in_sizes, int n_in,
                              void* d_out, int out_size, void* d_ws, size_t ws_size,
                              hipStream_t stream) {
  const float* x = (const float*)d_in[0];
  const int* mask = (const int*)d_in[1];
  const float* Wq = (const float*)d_in[2];
  const float* bq = (const float*)d_in[3];
  const float* Wk = (const float*)d_in[4];
  const float* bk = (const float*)d_in[5];
  const float* gq = (const float*)d_in[6];
  const float* bq_n = (const float*)d_in[7];
  const float* gk = (const float*)d_in[8];
  const float* bk_n = (const float*)d_in[9];
  float* out = (float*)d_out;

  char* ws = (char*)d_ws;
  const size_t MB = 1024 * 1024;

  if (ws_size >= 40 * MB) {
    // fused layout (40 MB): P2 bf16 [4096][2048] @0 (16), xbf @16 (8, Kbf aliases),
    // Wt @24 (4), Qbf @28 (8), msym @36 (4)
    unsigned short* P2 = (unsigned short*)ws;
    unsigned short* xbf = (unsigned short*)(ws + 16 * MB);
    unsigned short* Kbf = (unsigned short*)(ws + 16 * MB);   // alias: xbf dead after gemm
    unsigned short* Wt = (unsigned short*)(ws + 24 * MB);
    unsigned short* Qbf = (unsigned short*)(ws + 28 * MB);
    unsigned char* msym = (unsigned char*)(ws + 36 * MB);

    prep_kernel<<<8192, 256, 0, stream>>>(mask, x, Wq, Wk, msym, xbf, Wt);
    gemm_mfma_kernel<<<512, 256, 0, stream>>>(xbf, Wt, P2, 2048);
    ln_relu_bf_kernel<<<4096, 256, 0, stream>>>(P2, 2048, 0, bq, gq, bq_n, Qbf);
    ln_relu_bf_kernel<<<4096, 256, 0, stream>>>(P2, 2048, 1024, bk, gk, bk_n, Kbf);
    attn5_kernel<<<256, 1024, 0, stream>>>(Qbf, Kbf, msym, out);
  } else {
    // split layout (32 MB): P bf16 [4096][1024] @0 (8), xbf @8 (8, Kbf aliases),
    // Wt @16 (4), Qbf @20 (8), msym @28 (4)
    unsigned short* P = (unsigned short*)ws;
    unsigned short* xbf = (unsigned short*)(ws + 8 * MB);
    unsigned short* Kbf = (unsigned short*)(ws + 8 * MB);    // alias: xbf dead after 2nd gemm
    unsigned short* Wt = (unsigned short*)(ws + 16 * MB);
    unsigned short* Qbf = (unsigned short*)(ws + 20 * MB);
    unsigned char* msym = (unsigned char*)(ws + 28 * MB);

    prep_kernel<<<8192, 256, 0, stream>>>(mask, x, Wq, Wk, msym, xbf, Wt);
    gemm_mfma_kernel<<<256, 256, 0, stream>>>(xbf, Wt, P, 1024);
    ln_relu_bf_kernel<<<4096, 256, 0, stream>>>(P, 1024, 0, bq, gq, bq_n, Qbf);
    gemm_mfma_kernel<<<256, 256, 0, stream>>>(xbf, Wt + (size_t)1024 * 1024, P, 1024);
    ln_relu_bf_kernel<<<4096, 256, 0, stream>>>(P, 1024, 0, bk, gk, bk_n, Kbf);
    attn5_kernel<<<256, 1024, 0, stream>>>(Qbf, Kbf, msym, out);
  }
}

// Round 11
// 197.206 us; speedup vs baseline: 2.0969x; 1.0095x over previous
//
#include <hip/hip_runtime.h>
#include <hip/hip_bf16.h>

#define B_ 4
#define S_ 1024
#define E_ 1024
#define H_ 16
#define D_ 64

typedef __attribute__((ext_vector_type(8))) short short8;
typedef __attribute__((ext_vector_type(4))) float f32x4;

static __device__ __forceinline__ unsigned short f2bf(float x) {
  unsigned int u = __float_as_uint(x);
  unsigned int r = u + 0x7fffu + ((u >> 16) & 1u);  // round-to-nearest-even
  return (unsigned short)(r >> 16);
}
static __device__ __forceinline__ float bf2f(unsigned short b) {
  return __uint_as_float((unsigned int)b << 16);
}

#define GL2LDS16(g, l)                                                            \
  __builtin_amdgcn_global_load_lds(                                               \
      (const __attribute__((address_space(1))) unsigned int*)(g),                 \
      (__attribute__((address_space(3))) unsigned int*)(l), 16, 0, 0)

// ---------- fused preprocessing: mask|mask^T, x->bf16, W->Wt bf16 ----------
// blocks 0..4095: mask_sym; 4096..6143: cvt_x; 6144..8191: wt transpose
__global__ __launch_bounds__(256) void prep_kernel(const int* __restrict__ mask,
                                                   const float* __restrict__ x,
                                                   const float* __restrict__ Wq,
                                                   const float* __restrict__ Wk,
                                                   unsigned char* __restrict__ msym,
                                                   unsigned short* __restrict__ xbf,
                                                   unsigned short* __restrict__ Wt) {
  __shared__ __align__(16) char u_lds[32 * 33 * 4];
  const int blk = blockIdx.x;
  const int tid = threadIdx.x;
  if (blk < 4096) {
    int (*T)[33] = (int(*)[33])u_lds;
    const int b = blk >> 10;
    const int rest = blk & 1023;
    const int i0 = (rest >> 5) << 5;
    const int j0 = (rest & 31) << 5;
    const int ii = tid >> 3;
    const int jj4 = (tid & 7) << 2;
    const size_t bO = (size_t)b * S_ * S_;
    const int4 m2 = *(const int4*)&mask[bO + (size_t)(j0 + ii) * S_ + i0 + jj4];
    T[ii][jj4 + 0] = m2.x; T[ii][jj4 + 1] = m2.y; T[ii][jj4 + 2] = m2.z; T[ii][jj4 + 3] = m2.w;
    __syncthreads();
    const int4 m1 = *(const int4*)&mask[bO + (size_t)(i0 + ii) * S_ + j0 + jj4];
    uchar4 o;
    o.x = ((m1.x != 0) || (T[jj4 + 0][ii] != 0)) ? 1 : 0;
    o.y = ((m1.y != 0) || (T[jj4 + 1][ii] != 0)) ? 1 : 0;
    o.z = ((m1.z != 0) || (T[jj4 + 2][ii] != 0)) ? 1 : 0;
    o.w = ((m1.w != 0) || (T[jj4 + 3][ii] != 0)) ? 1 : 0;
    *(uchar4*)&msym[bO + (size_t)(i0 + ii) * S_ + j0 + jj4] = o;
  } else if (blk < 6144) {
    const size_t i = ((size_t)(blk - 4096) * 256 + tid) * 8;
    const float4 a = *(const float4*)(x + i);
    const float4 b = *(const float4*)(x + i + 4);
    const ushort4 p0 = {f2bf(a.x), f2bf(a.y), f2bf(a.z), f2bf(a.w)};
    const ushort4 p1 = {f2bf(b.x), f2bf(b.y), f2bf(b.z), f2bf(b.w)};
    *(ushort4*)(xbf + i) = p0;
    *(ushort4*)(xbf + i + 4) = p1;
  } else {
    unsigned short (*T2)[36] = (unsigned short(*)[36])u_lds;
    const int wblk = blk - 6144;           // 2 * 32 * 32
    const int mat = wblk >> 10;
    const int kt = (wblk >> 5) & 31, ntb = wblk & 31;
    const float* W = mat ? Wk : Wq;
    const int r = tid >> 3, c4 = (tid & 7) << 2;
    const float4 v = *(const float4*)&W[(size_t)(kt * 32 + r) * 1024 + ntb * 32 + c4];
    T2[r][c4 + 0] = f2bf(v.x); T2[r][c4 + 1] = f2bf(v.y);
    T2[r][c4 + 2] = f2bf(v.z); T2[r][c4 + 3] = f2bf(v.w);
    __syncthreads();
    const ushort4 o = {T2[c4 + 0][r], T2[c4 + 1][r], T2[c4 + 2][r], T2[c4 + 3][r]};
    *(ushort4*)&Wt[(size_t)(mat * 1024 + ntb * 32 + r) * 1024 + kt * 32 + c4] = o;
  }
}

// ------- bf16 MFMA GEMM, BK=64: P[4096][nstride] = xbf[4096][1024] @ Wt^T --------
__global__ __launch_bounds__(256) void gemm_mfma_kernel(const unsigned short* __restrict__ Abf,
                                                        const unsigned short* __restrict__ Wt,
                                                        unsigned short* __restrict__ P,
                                                        int nstride) {
  __shared__ __align__(16) unsigned short As[128 * 64];  // 16 KB, [m][k]
  __shared__ __align__(16) unsigned short Bs[128 * 64];  // 16 KB, [n][k]
  const int tid = threadIdx.x;
  const int m0 = (blockIdx.x & 31) << 7;
  const int n0 = (blockIdx.x >> 5) << 7;
  const int wave = tid >> 6, lane = tid & 63;
  const int ln15 = lane & 15, rg = lane >> 4;
  const int wm = (wave & 1) << 6;
  const int wn = (wave >> 1) << 6;
  const int sr = tid >> 3;
  const int sc = (tid & 7) << 3;
  const unsigned short* gA = Abf + (size_t)(m0 + sr) * 1024 + sc;
  const unsigned short* gB = Wt + (size_t)(n0 + sr) * 1024 + sc;
  unsigned short* lA = As + tid * 8;
  unsigned short* lB = Bs + tid * 8;
  f32x4 acc[4][4];
#pragma unroll
  for (int i = 0; i < 4; ++i)
#pragma unroll
    for (int j = 0; j < 4; ++j) acc[i][j] = (f32x4){0.0f, 0.0f, 0.0f, 0.0f};

  const unsigned short* pa = As + (wm + ln15) * 64 + rg * 8;
  const unsigned short* pb = Bs + (wn + ln15) * 64 + rg * 8;
  for (int k0 = 0; k0 < E_; k0 += 64) {
#pragma unroll
    for (int j = 0; j < 4; ++j) {
      GL2LDS16(gA + k0 + (size_t)(j * 32) * 1024, lA + j * 2048);
      GL2LDS16(gB + k0 + (size_t)(j * 32) * 1024, lB + j * 2048);
    }
    __syncthreads();
#pragma unroll
    for (int kk = 0; kk < 2; ++kk) {
      short8 af[4], bfr[4];
#pragma unroll
      for (int i = 0; i < 4; ++i) af[i] = *(const short8*)(pa + i * 16 * 64 + kk * 32);
#pragma unroll
      for (int j = 0; j < 4; ++j) bfr[j] = *(const short8*)(pb + j * 16 * 64 + kk * 32);
#pragma unroll
      for (int i = 0; i < 4; ++i)
#pragma unroll
        for (int j = 0; j < 4; ++j)
          acc[i][j] = __builtin_amdgcn_mfma_f32_16x16x32_bf16(af[i], bfr[j], acc[i][j], 0, 0, 0);
    }
    __syncthreads();
  }
#pragma unroll
  for (int i = 0; i < 4; ++i)
#pragma unroll
    for (int j = 0; j < 4; ++j)
#pragma unroll
      for (int r = 0; r < 4; ++r) {
        const int row = m0 + wm + i * 16 + rg * 4 + r;
        const int col = n0 + wn + j * 16 + ln15;
        P[(size_t)row * nstride + col] = f2bf(acc[i][j][r]);
      }
}

// ---- bias+LN+ReLU from bf16 P; emit bf16 head-major [b*16+h][s][d] ----
__device__ __forceinline__ void ln_body(const unsigned short* p, const float* bias,
                                        const float* gamma, const float* beta,
                                        unsigned short* obf, int b, int s, int tid) {
  const ushort4 pv = *(const ushort4*)(p + tid * 4);
  float4 v = {bf2f(pv.x), bf2f(pv.y), bf2f(pv.z), bf2f(pv.w)};
  const float4 bb = ((const float4*)bias)[tid];
  v.x += bb.x; v.y += bb.y; v.z += bb.z; v.w += bb.w;
  float sum = v.x + v.y + v.z + v.w;
  float s2 = v.x * v.x + v.y * v.y + v.z * v.z + v.w * v.w;
#pragma unroll
  for (int off = 32; off >= 1; off >>= 1) {
    sum += __shfl_xor(sum, off);
    s2 += __shfl_xor(s2, off);
  }
  __shared__ float red[2][4];
  const int wave = tid >> 6, lane = tid & 63;
  if (lane == 0) { red[0][wave] = sum; red[1][wave] = s2; }
  __syncthreads();
  sum = red[0][0] + red[0][1] + red[0][2] + red[0][3];
  s2 = red[1][0] + red[1][1] + red[1][2] + red[1][3];
  const float mu = sum * (1.0f / E_);
  const float var = s2 * (1.0f / E_) - mu * mu;
  const float r = rsqrtf(var + 1e-5f);
  const float4 g = ((const float4*)gamma)[tid];
  const float4 bt = ((const float4*)beta)[tid];
  const float o0 = fmaxf((v.x - mu) * r * g.x + bt.x, 0.0f);
  const float o1 = fmaxf((v.y - mu) * r * g.y + bt.y, 0.0f);
  const float o2 = fmaxf((v.z - mu) * r * g.z + bt.z, 0.0f);
  const float o3 = fmaxf((v.w - mu) * r * g.w + bt.w, 0.0f);
  const int h = tid >> 4;
  const int d = (tid & 15) << 2;
  const ushort4 ob = {f2bf(o0), f2bf(o1), f2bf(o2), f2bf(o3)};
  *(ushort4*)&obf[((size_t)(b * H_ + h) * S_ + s) * D_ + d] = ob;
}

__global__ __launch_bounds__(256) void ln_relu_bf_kernel(const unsigned short* __restrict__ P,
                                                         int rowstride, int coloff,
                                                         const float* __restrict__ bias,
                                                         const float* __restrict__ gamma,
                                                         const float* __restrict__ beta,
                                                         unsigned short* __restrict__ obf) {
  const int row = blockIdx.x;
  ln_body(P + (size_t)row * rowstride + coloff, bias, gamma, beta, obf,
          row >> 10, row & 1023, threadIdx.x);
}

// fused both-LN launch (40MB path): blocks 0..4095 -> Q, 4096..8191 -> K
__global__ __launch_bounds__(256) void ln2_kernel(const unsigned short* __restrict__ P2,
                                                  const float* __restrict__ bq,
                                                  const float* __restrict__ gq,
                                                  const float* __restrict__ bqn,
                                                  const float* __restrict__ bk,
                                                  const float* __restrict__ gk,
                                                  const float* __restrict__ bkn,
                                                  unsigned short* __restrict__ Qbf,
                                                  unsigned short* __restrict__ Kbf) {
  const int blk = blockIdx.x;
  const int sel = blk >> 12;
  const int row = blk & 4095;
  ln_body(P2 + (size_t)row * 2048 + sel * 1024,
          sel ? bk : bq, sel ? gk : gq, sel ? bkn : bqn,
          sel ? Kbf : Qbf, row >> 10, row & 1023, threadIdx.x);
}

// ======= attention v8: 512-key half-tiles via async global_load_lds, 3 barriers/head ===
// block: (b, 16-q), grid 256, 1024 thr = 16 waves, 1 block/CU (LDS 129 KB).
// Per head: 2 steps of 512 keys; DMA for step s+1 issued at TOP of step s into the
// other 64KB buffer (issue-to-drain = full step >> L2 latency; drain at the step-end
// barrier's vmcnt(0)). Per step per wave: 4 MFMAs + 16 exps (4x fatter than r7).
// Q a-frags from global per head (identical across waves -> L1 broadcast).
// e fp32 in 16 regs; l via 16-lane shuffle + tid<16 cross-wave reduce.
// LDS K layout: row=key (128 B), chunk XOR-swizzle phys = c ^ (key&7).
// MFMA 16x16x32 bf16, C-layout: col(key)=lane&15, row(q)=(lane>>4)*4+reg.
__global__ __launch_bounds__(1024, 4) void attn8_kernel(const unsigned short* __restrict__ Qbf,
                                                        const unsigned short* __restrict__ Kbf,
                                                        const unsigned char* __restrict__ msym,
                                                        float* __restrict__ out) {
  __shared__ __align__(16) unsigned short Ks[2][512 * 64];  // 2 x 64 KB
  __shared__ __align__(16) float l_lds[16][16];             // [wave][q]
  __shared__ __align__(16) float linv[16];
  const int tid = threadIdx.x;
  const int wave = tid >> 6, lane = tid & 63;
  const int ln15 = lane & 15, rg = lane >> 4;
  const int b = blockIdx.x & 3;                 // XCD swizzle: K[b] L2-resident
  const int q0 = (blockIdx.x >> 2) << 4;
  const unsigned short* Kb = Kbf + (size_t)b * H_ * S_ * D_;
  const unsigned short* Qb = Qbf + (size_t)b * H_ * S_ * D_;

  // mask bits: bit(half*8 + jt*4 + r) = msym[q0+rg*4+r][half*512 + wave*32 + jt*16 + ln15]
  unsigned int mbits = 0;
#pragma unroll
  for (int half = 0; half < 2; ++half)
#pragma unroll
    for (int jt = 0; jt < 2; ++jt)
#pragma unroll
      for (int r = 0; r < 4; ++r)
        mbits |= (msym[((size_t)b * S_ + q0 + rg * 4 + r) * S_ + half * 512 + wave * 32 + jt * 16 + ln15]
                      ? 1u : 0u) << (half * 8 + jt * 4 + r);

  // DMA staging map: call c covers key = c*128 + (tid>>3), phys chunk tid&7,
  // global (logical) chunk = (tid&7) ^ (key&7); lds dst = c*16KB + tid*16.
  const int skey = tid >> 3;
  const int sgc = ((tid & 7) ^ (skey & 7)) << 3;   // shorts
  // prologue: DMA step 0 (h=0, half=0) into Ks[0]
#pragma unroll
  for (int c = 0; c < 4; ++c)
    GL2LDS16(Kb + (size_t)(c * 128 + skey) * D_ + sgc, Ks[0] + c * 8192 + tid * 8);
  __syncthreads();   // vmcnt(0) drain

  const int pfrag = (rg ^ (ln15 & 7)) * 8;  // swizzled chunk offset (shorts)
  float o[2][2][4] = {};
  float ef[2][2][4];
  float la[4];

#pragma unroll 1
  for (int h = 0; h < 16; ++h) {
    // A-frags from global: same 2KB for all 16 waves -> L1 broadcast
    const unsigned short* qrow = Qb + ((size_t)h * S_ + q0 + ln15) * D_ + rg * 8;
    const short8 a0 = *(const short8*)qrow;
    const short8 a1 = *(const short8*)(qrow + 32);
    la[0] = la[1] = la[2] = la[3] = 0.0f;
#pragma unroll
    for (int half = 0; half < 2; ++half) {
      const int s = h * 2 + half;
      // issue DMA for step s+1 into the other buffer (drained at this step's end barrier)
      if (s < 31) {
        const int h1 = (s + 1) >> 1, hf1 = (s + 1) & 1;
        const unsigned short* g = Kb + (size_t)h1 * (S_ * D_) + (size_t)(hf1 * 512 + skey) * D_ + sgc;
        unsigned short* lp = Ks[(s + 1) & 1] + tid * 8;
#pragma unroll
        for (int c = 0; c < 4; ++c)
          GL2LDS16(g + (size_t)(c * 128) * D_, lp + c * 8192);
      }
      // compute this 512-key half from Ks[s&1]
      const unsigned short* kw = Ks[s & 1] + (wave * 32 + ln15) * 64;
#pragma unroll
      for (int jt = 0; jt < 2; ++jt) {
        const unsigned short* kp = kw + jt * 16 * 64;
        const short8 b0 = *(const short8*)(kp + pfrag);
        const short8 b1 = *(const short8*)(kp + (pfrag ^ 32));
        f32x4 cc = {0.0f, 0.0f, 0.0f, 0.0f};
        cc = __builtin_amdgcn_mfma_f32_16x16x32_bf16(a0, b0, cc, 0, 0, 0);
        cc = __builtin_amdgcn_mfma_f32_16x16x32_bf16(a1, b1, cc, 0, 0, 0);
#pragma unroll
        for (int r = 0; r < 4; ++r) {
          const float sv = fminf(cc[r] * 0.125f, 80.0f);
          const float ev = ((mbits >> (half * 8 + jt * 4 + r)) & 1u) ? 0.0f : __expf(sv);
          ef[half][jt][r] = ev;
          la[r] += ev;
        }
      }
      if (half == 0) {
        __syncthreads();   // drain DMA for half 1 + release Ks[s&1] readers
      } else {
        // head end: 16-lane reduce, publish, cross-wave reduce, o update
#pragma unroll
        for (int r = 0; r < 4; ++r) {
          float lv = la[r];
          lv += __shfl_xor(lv, 1);
          lv += __shfl_xor(lv, 2);
          lv += __shfl_xor(lv, 4);
          lv += __shfl_xor(lv, 8);
          la[r] = lv;
        }
        if (ln15 == 0) *(float4*)&l_lds[wave][rg * 4] = (float4){la[0], la[1], la[2], la[3]};
        __syncthreads();   // drain DMA for next head + l_lds visible
        if (tid < 16) {
          float ssum = 0.0f;
#pragma unroll
          for (int w = 0; w < 16; ++w) ssum += l_lds[w][tid];
          linv[tid] = 0.0625f / ssum;   // 1/(16*l): head-mean folded in
        }
        __syncthreads();
        const float4 li4 = *(const float4*)&linv[rg * 4];
#pragma unroll
        for (int hf = 0; hf < 2; ++hf)
#pragma unroll
          for (int jt = 0; jt < 2; ++jt) {
            o[hf][jt][0] += ef[hf][jt][0] * li4.x;
            o[hf][jt][1] += ef[hf][jt][1] * li4.y;
            o[hf][jt][2] += ef[hf][jt][2] * li4.z;
            o[hf][jt][3] += ef[hf][jt][3] * li4.w;
          }
      }
    }
  }
  // direct stores: 64 B contiguous per (half,jt,r) across the 16 key-lanes
#pragma unroll
  for (int half = 0; half < 2; ++half)
#pragma unroll
    for (int jt = 0; jt < 2; ++jt)
#pragma unroll
      for (int r = 0; r < 4; ++r)
        out[((size_t)b * S_ + q0 + rg * 4 + r) * S_ + half * 512 + wave * 32 + jt * 16 + ln15] =
            o[half][jt][r];
}

extern "C" void kernel_launch(void* const* d_in, const int* in_sizes, int n_in,
                              void* d_out, int out_size, void* d_ws, size_t ws_size,
                              hipStream_t stream) {
  const float* x = (const float*)d_in[0];
  const int* mask = (const int*)d_in[1];
  const float* Wq = (const float*)d_in[2];
  const float* bq = (const float*)d_in[3];
  const float* Wk = (const float*)d_in[4];
  const float* bk = (const float*)d_in[5];
  const float* gq = (const float*)d_in[6];
  const float* bq_n = (const float*)d_in[7];
  const float* gk = (const float*)d_in[8];
  const float* bk_n = (const float*)d_in[9];
  float* out = (float*)d_out;

  char* ws = (char*)d_ws;
  const size_t MB = 1024 * 1024;

  if (ws_size >= 40 * MB) {
    // fused layout (40 MB): P2 bf16 [4096][2048] @0 (16), xbf @16 (8, Kbf aliases),
    // Wt @24 (4), Qbf @28 (8), msym @36 (4)
    unsigned short* P2 = (unsigned short*)ws;
    unsigned short* xbf = (unsigned short*)(ws + 16 * MB);
    unsigned short* Kbf = (unsigned short*)(ws + 16 * MB);   // alias: xbf dead after gemm
    unsigned short* Wt = (unsigned short*)(ws + 24 * MB);
    unsigned short* Qbf = (unsigned short*)(ws + 28 * MB);
    unsigned char* msym = (unsigned char*)(ws + 36 * MB);

    prep_kernel<<<8192, 256, 0, stream>>>(mask, x, Wq, Wk, msym, xbf, Wt);
    gemm_mfma_kernel<<<512, 256, 0, stream>>>(xbf, Wt, P2, 2048);
    ln2_kernel<<<8192, 256, 0, stream>>>(P2, bq, gq, bq_n, bk, gk, bk_n, Qbf, Kbf);
    attn8_kernel<<<256, 1024, 0, stream>>>(Qbf, Kbf, msym, out);
  } else {
    // split layout (32 MB): P bf16 [4096][1024] @0 (8), xbf @8 (8, Kbf aliases),
    // Wt @16 (4), Qbf @20 (8), msym @28 (4)
    unsigned short* P = (unsigned short*)ws;
    unsigned short* xbf = (unsigned short*)(ws + 8 * MB);
    unsigned short* Kbf = (unsigned short*)(ws + 8 * MB);    // alias: xbf dead after 2nd gemm
    unsigned short* Wt = (unsigned short*)(ws + 16 * MB);
    unsigned short* Qbf = (unsigned short*)(ws + 20 * MB);
    unsigned char* msym = (unsigned char*)(ws + 28 * MB);

    prep_kernel<<<8192, 256, 0, stream>>>(mask, x, Wq, Wk, msym, xbf, Wt);
    gemm_mfma_kernel<<<256, 256, 0, stream>>>(xbf, Wt, P, 1024);
    ln_relu_bf_kernel<<<4096, 256, 0, stream>>>(P, 1024, 0, bq, gq, bq_n, Qbf);
    gemm_mfma_kernel<<<256, 256, 0, stream>>>(xbf, Wt + (size_t)1024 * 1024, P, 1024);
    ln_relu_bf_kernel<<<4096, 256, 0, stream>>>(P, 1024, 0, bk, gk, bk_n, Kbf);
    attn8_kernel<<<256, 1024, 0, stream>>>(Qbf, Kbf, msym, out);
  }
}

// Round 12
// 194.236 us; speedup vs baseline: 2.1289x; 1.0153x over previous
//
#include <hip/hip_runtime.h>
#include <hip/hip_bf16.h>

#define B_ 4
#define S_ 1024
#define E_ 1024
#define H_ 16
#define D_ 64

typedef __attribute__((ext_vector_type(8))) short short8;
typedef __attribute__((ext_vector_type(4))) float f32x4;

static __device__ __forceinline__ unsigned short f2bf(float x) {
  unsigned int u = __float_as_uint(x);
  unsigned int r = u + 0x7fffu + ((u >> 16) & 1u);  // round-to-nearest-even
  return (unsigned short)(r >> 16);
}
static __device__ __forceinline__ float bf2f(unsigned short b) {
  return __uint_as_float((unsigned int)b << 16);
}

#define GL2LDS16(g, l)                                                            \
  __builtin_amdgcn_global_load_lds(                                               \
      (const __attribute__((address_space(1))) unsigned int*)(g),                 \
      (__attribute__((address_space(3))) unsigned int*)(l), 16, 0, 0)

// gfx9 s_waitcnt imm: vmcnt[3:0]|[15:14], expcnt[6:4], lgkmcnt[11:8].
// vmcnt(4), expcnt/lgkmcnt free = 0x0F74.
#define WAIT_VMCNT4() __builtin_amdgcn_s_waitcnt(0x0F74)

// ---------- fused preprocessing: mask|mask^T, x->bf16, W->Wt bf16 ----------
// blocks 0..4095: mask_sym; 4096..6143: cvt_x; 6144..8191: wt transpose
__global__ __launch_bounds__(256) void prep_kernel(const int* __restrict__ mask,
                                                   const float* __restrict__ x,
                                                   const float* __restrict__ Wq,
                                                   const float* __restrict__ Wk,
                                                   unsigned char* __restrict__ msym,
                                                   unsigned short* __restrict__ xbf,
                                                   unsigned short* __restrict__ Wt) {
  __shared__ __align__(16) char u_lds[32 * 33 * 4];
  const int blk = blockIdx.x;
  const int tid = threadIdx.x;
  if (blk < 4096) {
    int (*T)[33] = (int(*)[33])u_lds;
    const int b = blk >> 10;
    const int rest = blk & 1023;
    const int i0 = (rest >> 5) << 5;
    const int j0 = (rest & 31) << 5;
    const int ii = tid >> 3;
    const int jj4 = (tid & 7) << 2;
    const size_t bO = (size_t)b * S_ * S_;
    const int4 m2 = *(const int4*)&mask[bO + (size_t)(j0 + ii) * S_ + i0 + jj4];
    T[ii][jj4 + 0] = m2.x; T[ii][jj4 + 1] = m2.y; T[ii][jj4 + 2] = m2.z; T[ii][jj4 + 3] = m2.w;
    __syncthreads();
    const int4 m1 = *(const int4*)&mask[bO + (size_t)(i0 + ii) * S_ + j0 + jj4];
    uchar4 o;
    o.x = ((m1.x != 0) || (T[jj4 + 0][ii] != 0)) ? 1 : 0;
    o.y = ((m1.y != 0) || (T[jj4 + 1][ii] != 0)) ? 1 : 0;
    o.z = ((m1.z != 0) || (T[jj4 + 2][ii] != 0)) ? 1 : 0;
    o.w = ((m1.w != 0) || (T[jj4 + 3][ii] != 0)) ? 1 : 0;
    *(uchar4*)&msym[bO + (size_t)(i0 + ii) * S_ + j0 + jj4] = o;
  } else if (blk < 6144) {
    const size_t i = ((size_t)(blk - 4096) * 256 + tid) * 8;
    const float4 a = *(const float4*)(x + i);
    const float4 b = *(const float4*)(x + i + 4);
    const ushort4 p0 = {f2bf(a.x), f2bf(a.y), f2bf(a.z), f2bf(a.w)};
    const ushort4 p1 = {f2bf(b.x), f2bf(b.y), f2bf(b.z), f2bf(b.w)};
    *(ushort4*)(xbf + i) = p0;
    *(ushort4*)(xbf + i + 4) = p1;
  } else {
    unsigned short (*T2)[36] = (unsigned short(*)[36])u_lds;
    const int wblk = blk - 6144;           // 2 * 32 * 32
    const int mat = wblk >> 10;
    const int kt = (wblk >> 5) & 31, ntb = wblk & 31;
    const float* W = mat ? Wk : Wq;
    const int r = tid >> 3, c4 = (tid & 7) << 2;
    const float4 v = *(const float4*)&W[(size_t)(kt * 32 + r) * 1024 + ntb * 32 + c4];
    T2[r][c4 + 0] = f2bf(v.x); T2[r][c4 + 1] = f2bf(v.y);
    T2[r][c4 + 2] = f2bf(v.z); T2[r][c4 + 3] = f2bf(v.w);
    __syncthreads();
    const ushort4 o = {T2[c4 + 0][r], T2[c4 + 1][r], T2[c4 + 2][r], T2[c4 + 3][r]};
    *(ushort4*)&Wt[(size_t)(mat * 1024 + ntb * 32 + r) * 1024 + kt * 32 + c4] = o;
  }
}

// ------- bf16 MFMA GEMM, BK=64: P[4096][nstride] = xbf[4096][1024] @ Wt^T --------
__global__ __launch_bounds__(256) void gemm_mfma_kernel(const unsigned short* __restrict__ Abf,
                                                        const unsigned short* __restrict__ Wt,
                                                        unsigned short* __restrict__ P,
                                                        int nstride) {
  __shared__ __align__(16) unsigned short As[128 * 64];  // 16 KB, [m][k]
  __shared__ __align__(16) unsigned short Bs[128 * 64];  // 16 KB, [n][k]
  const int tid = threadIdx.x;
  const int m0 = (blockIdx.x & 31) << 7;
  const int n0 = (blockIdx.x >> 5) << 7;
  const int wave = tid >> 6, lane = tid & 63;
  const int ln15 = lane & 15, rg = lane >> 4;
  const int wm = (wave & 1) << 6;
  const int wn = (wave >> 1) << 6;
  const int sr = tid >> 3;
  const int sc = (tid & 7) << 3;
  const unsigned short* gA = Abf + (size_t)(m0 + sr) * 1024 + sc;
  const unsigned short* gB = Wt + (size_t)(n0 + sr) * 1024 + sc;
  unsigned short* lA = As + tid * 8;
  unsigned short* lB = Bs + tid * 8;
  f32x4 acc[4][4];
#pragma unroll
  for (int i = 0; i < 4; ++i)
#pragma unroll
    for (int j = 0; j < 4; ++j) acc[i][j] = (f32x4){0.0f, 0.0f, 0.0f, 0.0f};

  const unsigned short* pa = As + (wm + ln15) * 64 + rg * 8;
  const unsigned short* pb = Bs + (wn + ln15) * 64 + rg * 8;
  for (int k0 = 0; k0 < E_; k0 += 64) {
#pragma unroll
    for (int j = 0; j < 4; ++j) {
      GL2LDS16(gA + k0 + (size_t)(j * 32) * 1024, lA + j * 2048);
      GL2LDS16(gB + k0 + (size_t)(j * 32) * 1024, lB + j * 2048);
    }
    __syncthreads();
#pragma unroll
    for (int kk = 0; kk < 2; ++kk) {
      short8 af[4], bfr[4];
#pragma unroll
      for (int i = 0; i < 4; ++i) af[i] = *(const short8*)(pa + i * 16 * 64 + kk * 32);
#pragma unroll
      for (int j = 0; j < 4; ++j) bfr[j] = *(const short8*)(pb + j * 16 * 64 + kk * 32);
#pragma unroll
      for (int i = 0; i < 4; ++i)
#pragma unroll
        for (int j = 0; j < 4; ++j)
          acc[i][j] = __builtin_amdgcn_mfma_f32_16x16x32_bf16(af[i], bfr[j], acc[i][j], 0, 0, 0);
    }
    __syncthreads();
  }
#pragma unroll
  for (int i = 0; i < 4; ++i)
#pragma unroll
    for (int j = 0; j < 4; ++j)
#pragma unroll
      for (int r = 0; r < 4; ++r) {
        const int row = m0 + wm + i * 16 + rg * 4 + r;
        const int col = n0 + wn + j * 16 + ln15;
        P[(size_t)row * nstride + col] = f2bf(acc[i][j][r]);
      }
}

// ---- bias+LN+ReLU from bf16 P; emit bf16 head-major [b*16+h][s][d] ----
__device__ __forceinline__ void ln_body(const unsigned short* p, const float* bias,
                                        const float* gamma, const float* beta,
                                        unsigned short* obf, int b, int s, int tid) {
  const ushort4 pv = *(const ushort4*)(p + tid * 4);
  float4 v = {bf2f(pv.x), bf2f(pv.y), bf2f(pv.z), bf2f(pv.w)};
  const float4 bb = ((const float4*)bias)[tid];
  v.x += bb.x; v.y += bb.y; v.z += bb.z; v.w += bb.w;
  float sum = v.x + v.y + v.z + v.w;
  float s2 = v.x * v.x + v.y * v.y + v.z * v.z + v.w * v.w;
#pragma unroll
  for (int off = 32; off >= 1; off >>= 1) {
    sum += __shfl_xor(sum, off);
    s2 += __shfl_xor(s2, off);
  }
  __shared__ float red[2][4];
  const int wave = tid >> 6, lane = tid & 63;
  if (lane == 0) { red[0][wave] = sum; red[1][wave] = s2; }
  __syncthreads();
  sum = red[0][0] + red[0][1] + red[0][2] + red[0][3];
  s2 = red[1][0] + red[1][1] + red[1][2] + red[1][3];
  const float mu = sum * (1.0f / E_);
  const float var = s2 * (1.0f / E_) - mu * mu;
  const float r = rsqrtf(var + 1e-5f);
  const float4 g = ((const float4*)gamma)[tid];
  const float4 bt = ((const float4*)beta)[tid];
  const float o0 = fmaxf((v.x - mu) * r * g.x + bt.x, 0.0f);
  const float o1 = fmaxf((v.y - mu) * r * g.y + bt.y, 0.0f);
  const float o2 = fmaxf((v.z - mu) * r * g.z + bt.z, 0.0f);
  const float o3 = fmaxf((v.w - mu) * r * g.w + bt.w, 0.0f);
  const int h = tid >> 4;
  const int d = (tid & 15) << 2;
  const ushort4 ob = {f2bf(o0), f2bf(o1), f2bf(o2), f2bf(o3)};
  *(ushort4*)&obf[((size_t)(b * H_ + h) * S_ + s) * D_ + d] = ob;
}

__global__ __launch_bounds__(256) void ln_relu_bf_kernel(const unsigned short* __restrict__ P,
                                                         int rowstride, int coloff,
                                                         const float* __restrict__ bias,
                                                         const float* __restrict__ gamma,
                                                         const float* __restrict__ beta,
                                                         unsigned short* __restrict__ obf) {
  const int row = blockIdx.x;
  ln_body(P + (size_t)row * rowstride + coloff, bias, gamma, beta, obf,
          row >> 10, row & 1023, threadIdx.x);
}

// fused both-LN launch (40MB path): blocks 0..4095 -> Q, 4096..8191 -> K
__global__ __launch_bounds__(256) void ln2_kernel(const unsigned short* __restrict__ P2,
                                                  const float* __restrict__ bq,
                                                  const float* __restrict__ gq,
                                                  const float* __restrict__ bqn,
                                                  const float* __restrict__ bk,
                                                  const float* __restrict__ gk,
                                                  const float* __restrict__ bkn,
                                                  unsigned short* __restrict__ Qbf,
                                                  unsigned short* __restrict__ Kbf) {
  const int blk = blockIdx.x;
  const int sel = blk >> 12;
  const int row = blk & 4095;
  ln_body(P2 + (size_t)row * 2048 + sel * 1024,
          sel ? bk : bq, sel ? gk : gq, sel ? bkn : bqn,
          sel ? Kbf : Qbf, row >> 10, row & 1023, threadIdx.x);
}

// ======= attention v9: WAVE-PRIVATE async K staging, 1 barrier per head =======
// block: (b, 16-q), grid 256, 1024 thr = 16 waves, 1 block/CU (LDS 130 KB).
// Each wave owns keys [wave*32, wave*32+32) of each 512-key half and DMAs ITS OWN
// 4 KB slice via global_load_lds into a private region of Ks[2] (step-parity
// ping-pong). No barriers for staging: wave-local s_waitcnt vmcnt(4) keeps the
// next step's 4 DMAs in flight while guaranteeing this step's slice landed.
// Even steps after a barrier need no wait (syncthreads drained vmcnt).
// Softmax l: wave-local 16-lane butterfly -> transposed partials in LDS ->
// ONE barrier -> each lane reads wave-ln15's partial (b128) and butterflies
// across waves -> linv computed in-lane (no second barrier). 16 barriers total.
// MFMA 16x16x32 bf16, C-layout: col(key)=lane&15, row(q)=(lane>>4)*4+reg.
__global__ __launch_bounds__(1024, 4) void attn9_kernel(const unsigned short* __restrict__ Qbf,
                                                        const unsigned short* __restrict__ Kbf,
                                                        const unsigned char* __restrict__ msym,
                                                        float* __restrict__ out) {
  __shared__ __align__(16) unsigned short Ks[2][16][2048];  // [par][wave][32 keys x 64] 128 KB
  __shared__ __align__(16) float l_lds[2][16][16];          // [par][wave][q] 2 KB
  const int tid = threadIdx.x;
  const int wave = tid >> 6, lane = tid & 63;
  const int ln15 = lane & 15, rg = lane >> 4;
  const int b = blockIdx.x & 3;                 // XCD swizzle: K[b] L2-resident
  const int q0 = (blockIdx.x >> 2) << 4;
  const unsigned short* Kb = Kbf + (size_t)b * H_ * S_ * D_;
  const unsigned short* Qb = Qbf + (size_t)b * H_ * S_ * D_;

  // mask bits: bit(hf*8 + jt*4 + r) = msym[q0+rg*4+r][hf*512 + wave*32 + jt*16 + ln15]
  unsigned int mbits = 0;
#pragma unroll
  for (int hf = 0; hf < 2; ++hf)
#pragma unroll
    for (int jt = 0; jt < 2; ++jt)
#pragma unroll
      for (int r = 0; r < 4; ++r)
        mbits |= (msym[((size_t)b * S_ + q0 + rg * 4 + r) * S_ + hf * 512 + wave * 32 + jt * 16 + ln15]
                      ? 1u : 0u) << (hf * 8 + jt * 4 + r);

  // DMA lane mapping (shorts): key_local = i*8 + (lane>>3), phys slot = lane&7,
  // global chunk = (lane&7) ^ (lane>>3)  [XOR swizzle; i*8 doesn't affect &7]
  const int gl = ((lane >> 3) << 6) + (((lane & 7) ^ (lane >> 3)) << 3);
  const unsigned short* gwave = Kb + wave * 2048 + gl;   // + hf*32768 + h*65536 + i*512
  // prologue: DMA steps 0 and 1 (head 0, halves 0/1) into Ks[0]/Ks[1]
#pragma unroll
  for (int c = 0; c < 4; ++c) GL2LDS16(gwave + c * 512, &Ks[0][wave][c * 512]);
#pragma unroll
  for (int c = 0; c < 4; ++c) GL2LDS16(gwave + 32768 + c * 512, &Ks[1][wave][c * 512]);

  const int pfrag = (rg ^ (ln15 & 7)) * 8;  // swizzled chunk offset (shorts)
  float o[2][2][4] = {};
  float ef[2][2][4];
  float la[4];

#pragma unroll 1
  for (int h = 0; h < 16; ++h) {
    // A-frags from global: same 2KB for all 16 waves -> L1 broadcast
    const unsigned short* qrow = Qb + ((size_t)h * S_ + q0 + ln15) * D_ + rg * 8;
    const short8 a0 = *(const short8*)qrow;
    const short8 a1 = *(const short8*)(qrow + 32);
    la[0] = la[1] = la[2] = la[3] = 0.0f;
#pragma unroll
    for (int hf = 0; hf < 2; ++hf) {
      const int s = h * 2 + hf;
      // issue DMA for step s+1 into wave's slice of the other buffer
      if (s < 31) {
        const int s1 = s + 1;
        const unsigned short* g = gwave + (size_t)(s1 >> 1) * 65536 + (s1 & 1) * 32768;
        unsigned short* lp = &Ks[s1 & 1][wave][0];
#pragma unroll
        for (int c = 0; c < 4; ++c) GL2LDS16(g + c * 512, lp + c * 512);
      }
      // wait for this step's slice: odd steps (and step 0) via wave-local vmcnt(4);
      // even steps s>=2 were drained by the previous head's barrier.
      if (s == 0 || (s & 1)) WAIT_VMCNT4();
      const unsigned short* kw = &Ks[s & 1][wave][ln15 * 64];
#pragma unroll
      for (int jt = 0; jt < 2; ++jt) {
        const unsigned short* kp = kw + jt * 1024;
        const short8 b0 = *(const short8*)(kp + pfrag);
        const short8 b1 = *(const short8*)(kp + (pfrag ^ 32));
        f32x4 cc = {0.0f, 0.0f, 0.0f, 0.0f};
        cc = __builtin_amdgcn_mfma_f32_16x16x32_bf16(a0, b0, cc, 0, 0, 0);
        cc = __builtin_amdgcn_mfma_f32_16x16x32_bf16(a1, b1, cc, 0, 0, 0);
#pragma unroll
        for (int r = 0; r < 4; ++r) {
          const float sv = fminf(cc[r] * 0.125f, 80.0f);
          const float ev = ((mbits >> (hf * 8 + jt * 4 + r)) & 1u) ? 0.0f : __expf(sv);
          ef[hf][jt][r] = ev;
          la[r] += ev;
        }
      }
    }
    // wave-local l: butterfly over the 16 key-lanes per q-row
#pragma unroll
    for (int r = 0; r < 4; ++r) {
      float lv = la[r];
      lv += __shfl_xor(lv, 1);
      lv += __shfl_xor(lv, 2);
      lv += __shfl_xor(lv, 4);
      lv += __shfl_xor(lv, 8);
      la[r] = lv;
    }
    if (ln15 == 0) *(float4*)&l_lds[h & 1][wave][rg * 4] = (float4){la[0], la[1], la[2], la[3]};
    __syncthreads();  // ONE barrier per head: l exchange (+ drains next-step DMA, landed)
    // cross-wave reduce without a second barrier: lane reads wave-ln15's partial
    const float4 pw = *(const float4*)&l_lds[h & 1][ln15][rg * 4];
    float p[4] = {pw.x, pw.y, pw.z, pw.w};
#pragma unroll
    for (int r = 0; r < 4; ++r) {
      float lv = p[r];
      lv += __shfl_xor(lv, 1);
      lv += __shfl_xor(lv, 2);
      lv += __shfl_xor(lv, 4);
      lv += __shfl_xor(lv, 8);
      p[r] = lv;
    }
#pragma unroll
    for (int r = 0; r < 4; ++r) {
      const float li = 0.0625f * __builtin_amdgcn_rcpf(p[r]);
#pragma unroll
      for (int hf = 0; hf < 2; ++hf)
#pragma unroll
        for (int jt = 0; jt < 2; ++jt) o[hf][jt][r] += ef[hf][jt][r] * li;
    }
  }
  // direct stores: 64 B contiguous per (hf,jt,r) across the 16 key-lanes
#pragma unroll
  for (int hf = 0; hf < 2; ++hf)
#pragma unroll
    for (int jt = 0; jt < 2; ++jt)
#pragma unroll
      for (int r = 0; r < 4; ++r)
        out[((size_t)b * S_ + q0 + rg * 4 + r) * S_ + hf * 512 + wave * 32 + jt * 16 + ln15] =
            o[hf][jt][r];
}

extern "C" void kernel_launch(void* const* d_in, const int* in_sizes, int n_in,
                              void* d_out, int out_size, void* d_ws, size_t ws_size,
                              hipStream_t stream) {
  const float* x = (const float*)d_in[0];
  const int* mask = (const int*)d_in[1];
  const float* Wq = (const float*)d_in[2];
  const float* bq = (const float*)d_in[3];
  const float* Wk = (const float*)d_in[4];
  const float* bk = (const float*)d_in[5];
  const float* gq = (const float*)d_in[6];
  const float* bq_n = (const float*)d_in[7];
  const float* gk = (const float*)d_in[8];
  const float* bk_n = (const float*)d_in[9];
  float* out = (float*)d_out;

  char* ws = (char*)d_ws;
  const size_t MB = 1024 * 1024;

  if (ws_size >= 40 * MB) {
    // fused layout (40 MB): P2 bf16 [4096][2048] @0 (16), xbf @16 (8, Kbf aliases),
    // Wt @24 (4), Qbf @28 (8), msym @36 (4)
    unsigned short* P2 = (unsigned short*)ws;
    unsigned short* xbf = (unsigned short*)(ws + 16 * MB);
    unsigned short* Kbf = (unsigned short*)(ws + 16 * MB);   // alias: xbf dead after gemm
    unsigned short* Wt = (unsigned short*)(ws + 24 * MB);
    unsigned short* Qbf = (unsigned short*)(ws + 28 * MB);
    unsigned char* msym = (unsigned char*)(ws + 36 * MB);

    prep_kernel<<<8192, 256, 0, stream>>>(mask, x, Wq, Wk, msym, xbf, Wt);
    gemm_mfma_kernel<<<512, 256, 0, stream>>>(xbf, Wt, P2, 2048);
    ln2_kernel<<<8192, 256, 0, stream>>>(P2, bq, gq, bq_n, bk, gk, bk_n, Qbf, Kbf);
    attn9_kernel<<<256, 1024, 0, stream>>>(Qbf, Kbf, msym, out);
  } else {
    // split layout (32 MB): P bf16 [4096][1024] @0 (8), xbf @8 (8, Kbf aliases),
    // Wt @16 (4), Qbf @20 (8), msym @28 (4)
    unsigned short* P = (unsigned short*)ws;
    unsigned short* xbf = (unsigned short*)(ws + 8 * MB);
    unsigned short* Kbf = (unsigned short*)(ws + 8 * MB);    // alias: xbf dead after 2nd gemm
    unsigned short* Wt = (unsigned short*)(ws + 16 * MB);
    unsigned short* Qbf = (unsigned short*)(ws + 20 * MB);
    unsigned char* msym = (unsigned char*)(ws + 28 * MB);

    prep_kernel<<<8192, 256, 0, stream>>>(mask, x, Wq, Wk, msym, xbf, Wt);
    gemm_mfma_kernel<<<256, 256, 0, stream>>>(xbf, Wt, P, 1024);
    ln_relu_bf_kernel<<<4096, 256, 0, stream>>>(P, 1024, 0, bq, gq, bq_n, Qbf);
    gemm_mfma_kernel<<<256, 256, 0, stream>>>(xbf, Wt + (size_t)1024 * 1024, P, 1024);
    ln_relu_bf_kernel<<<4096, 256, 0, stream>>>(P, 1024, 0, bk, gk, bk_n, Kbf);
    attn9_kernel<<<256, 1024, 0, stream>>>(Qbf, Kbf, msym, out);
  }
}